// Round 1
// baseline (9.829 us; speedup 1.0000x reference)
//
#include <hip/hip_runtime.h>

#define N_QUBITS 15
#define BATCH 512

// Closed-form: out[b][q] = prod_{j<=q} cos(x[b][j] + params[j])
//
// Derivation: initial |0..0> is a product state; RX layer keeps it a product
// state with per-qubit P(z_q=1) = sin^2(theta_q/2), so E[(-1)^{z_q}] =
// cos(theta_q). The CNOT ladder (applied sequentially, each control being the
// already-updated bit) maps bit q -> XOR of z_0..z_q. CNOTs are permutations
// of basis states, so measurement statistics are classical:
//   ev_q = E[prod_{j<=q} (-1)^{z_j}] = prod_{j<=q} cos(theta_j)
// by independence of the z_j.
__global__ void qlayer_closed_form(const float* __restrict__ x,
                                   const float* __restrict__ params,
                                   float* __restrict__ out) {
    int b = blockIdx.x * blockDim.x + threadIdx.x;
    if (b >= BATCH) return;

    // params is tiny (15 floats) and L1-cached; read directly.
    double prod = 1.0;
#pragma unroll
    for (int q = 0; q < N_QUBITS; ++q) {
        double th = (double)x[b * N_QUBITS + q] + (double)params[q];
        prod *= cos(th);
        out[b * N_QUBITS + q] = (float)prod;
    }
}

extern "C" void kernel_launch(void* const* d_in, const int* in_sizes, int n_in,
                              void* d_out, int out_size, void* d_ws, size_t ws_size,
                              hipStream_t stream) {
    const float* x = (const float*)d_in[0];       // (512, 15) float32
    const float* params = (const float*)d_in[1];  // (15,) float32
    float* out = (float*)d_out;                   // (512, 15) float32

    const int block = 256;
    const int grid = (BATCH + block - 1) / block; // 2 blocks
    qlayer_closed_form<<<grid, block, 0, stream>>>(x, params, out);
}